// Round 15
// baseline (1490.721 us; speedup 1.0000x reference)
//
#include <hip/hip_runtime.h>
#include <math.h>

#define NN 50000
#define NE 600000
#define ECAP 230000  // capacity for filtered edges (actual ~175K)
#define DD 128
#define D3 384
#define NB_ 20
#define HH 64
#define NG_ 512
#define LSZ 180224   // shorts per layer of transposed-bf16 weights

typedef short v8s __attribute__((ext_vector_type(8)));
typedef short v4sh __attribute__((ext_vector_type(4)));
typedef float v4f __attribute__((ext_vector_type(4)));

__device__ __forceinline__ float silu_f(float z) { return z / (1.0f + expf(-z)); }

__device__ __forceinline__ short f2bf(float f) {
  unsigned u = __float_as_uint(f);
  u += 0x7FFF + ((u >> 16) & 1);          // RNE
  return (short)(u >> 16);
}
__device__ __forceinline__ float bf2f(short s) {
  return __uint_as_float(((unsigned)(unsigned short)s) << 16);
}
__device__ __forceinline__ void split2(float x, short& h, short& l) {
  h = f2bf(x);
  l = f2bf(x - bf2f(h));
}
// split a float4 and store hi/lo as short4 (8B LDS stores)
__device__ __forceinline__ void split_store4(float4 f, short* hp, short* lp) {
  short h0,l0,h1,l1,h2,l2,h3,l3;
  split2(f.x,h0,l0); split2(f.y,h1,l1); split2(f.z,h2,l2); split2(f.w,h3,l3);
  v4sh hv = {h0,h1,h2,h3}, lv = {l0,l1,l2,l3};
  *(v4sh*)hp = hv; *(v4sh*)lp = lv;
}
// 3-term Markidis split: acc += ah@bh + al@bh + ah@bl   (proven: absmax 4.3e9)
#define MFMA3(acc, ah, al, bh, bl) \
  acc = __builtin_amdgcn_mfma_f32_16x16x32_bf16(ah, bh, acc, 0, 0, 0); \
  acc = __builtin_amdgcn_mfma_f32_16x16x32_bf16(al, bh, acc, 0, 0, 0); \
  acc = __builtin_amdgcn_mfma_f32_16x16x32_bf16(ah, bl, acc, 0, 0, 0);

// ---------------- utility ----------------
__global__ void zero_f_kernel(float* __restrict__ p, long n) {
  long i = (long)blockIdx.x * blockDim.x + threadIdx.x;
  long s = (long)gridDim.x * blockDim.x;
  for (; i < n; i += s) p[i] = 0.0f;
}

__global__ void zero_i_kernel(int* __restrict__ p, long n) {
  long i = (long)blockIdx.x * blockDim.x + threadIdx.x;
  long s = (long)gridDim.x * blockDim.x;
  for (; i < n; i += s) p[i] = 0;
}

__global__ void init_x_kernel(const int* __restrict__ at_no, const float* __restrict__ emb,
                              float* __restrict__ x) {
  int i = blockIdx.x * blockDim.x + threadIdx.x;
  if (i >= NN * DD) return;
  x[i] = emb[at_no[i >> 7] * DD + (i & 127)];
}

// ---------------- weight prep: fp32 [K][N] -> transposed bf16 hi/lo [N][K] ----------------
__global__ void prep_w_kernel(const float* __restrict__ Wm1, const float* __restrict__ Wm2,
                              const float* __restrict__ U, const float* __restrict__ V,
                              const float* __restrict__ Wu1, const float* __restrict__ Wu2,
                              short* __restrict__ hi, short* __restrict__ lo) {
  int idx = blockIdx.x * 256 + threadIdx.x;
  if (idx >= 3 * LSZ) return;
  int l = idx / LSZ, r = idx % LSZ;
  const float* src; int K, N, nk;
  if (r < 16384)       { src = Wm1 + (size_t)l*16384; K = 128; N = 128; nk = r; }
  else if (r < 65536)  { src = Wm2 + (size_t)l*49152; K = 128; N = 384; nk = r - 16384; }
  else if (r < 81920)  { src = U   + (size_t)l*16384; K = 128; N = 128; nk = r - 65536; }
  else if (r < 98304)  { src = V   + (size_t)l*16384; K = 128; N = 128; nk = r - 81920; }
  else if (r < 131072) { src = Wu1 + (size_t)l*32768; K = 256; N = 128; nk = r - 98304; }
  else                 { src = Wu2 + (size_t)l*49152; K = 128; N = 384; nk = r - 131072; }
  int n = nk / K, k = nk - n * K;
  float xx = src[(size_t)k * N + n];
  short h = f2bf(xx);
  hi[idx] = h;
  lo[idx] = f2bf(xx - bf2f(h));
}

// ---------------- CSR build (dst-sorted), filtering dist>=CUTOFF edges ----------------
__global__ void hist_kernel(const int* __restrict__ ei, const float* __restrict__ pos,
                            int* __restrict__ counts) {
  int e = blockIdx.x * blockDim.x + threadIdx.x;
  if (e >= NE) return;
  int s = ei[e], d = ei[NE + e];
  float dx = pos[3*d]   - pos[3*s];
  float dy = pos[3*d+1] - pos[3*s+1];
  float dz = pos[3*d+2] - pos[3*s+2];
  float d2 = dx*dx + dy*dy + dz*dz + 1e-12f;
  if (d2 < 25.0f) atomicAdd(&counts[d], 1);
}

__global__ void scan_kernel(const int* __restrict__ counts, int* __restrict__ indptr, int n) {
  __shared__ int sm[1024];
  __shared__ int carry_s;
  if (threadIdx.x == 0) carry_s = 0;
  __syncthreads();
  for (int start = 0; start < n; start += 1024) {
    int i = start + (int)threadIdx.x;
    int val = (i < n) ? counts[i] : 0;
    sm[threadIdx.x] = val;
    __syncthreads();
    for (int off = 1; off < 1024; off <<= 1) {
      int t = (threadIdx.x >= (unsigned)off) ? sm[threadIdx.x - off] : 0;
      __syncthreads();
      sm[threadIdx.x] += t;
      __syncthreads();
    }
    int c = carry_s;
    if (i < n) indptr[i] = c + sm[threadIdx.x] - val;
    __syncthreads();
    if (threadIdx.x == 0) carry_s = c + sm[1023];
    __syncthreads();
  }
  if (threadIdx.x == 0) indptr[n] = carry_s;
}

__global__ void fill_kernel(const int* __restrict__ ei, const float* __restrict__ pos,
                            const int* __restrict__ indptr, int* __restrict__ cursor,
                            int* __restrict__ srcs, float4* __restrict__ eg1,
                            float4* __restrict__ eg2) {
  int e = blockIdx.x * blockDim.x + threadIdx.x;
  if (e >= NE) return;
  int s = ei[e], d = ei[NE + e];
  float dx = pos[3*d]   - pos[3*s];
  float dy = pos[3*d+1] - pos[3*s+1];
  float dz = pos[3*d+2] - pos[3*s+2];
  float d2 = dx*dx + dy*dy + dz*dz + 1e-12f;
  if (d2 < 25.0f) {
    int p = atomicAdd(&cursor[d], 1);
    int slot = indptr[d] + p;
    float dist = sqrtf(d2);
    float inv = 1.0f / dist;
    float wang = 0.62831853071795864769f * dist;   // pi*dist/CUTOFF
    float s1 = __sinf(wang), c1 = __cosf(wang);
    float fc = 0.5f * (c1 + 1.0f);
    srcs[slot] = s;
    eg1[slot] = make_float4(s1, c1, fc, fc * inv);
    eg2[slot] = make_float4(dx * inv, dy * inv, dz * inv, 0.0f);
  }
}

// ---------------- fused node MLP: phi = silu(x@Wm1+b1)@Wm2+b2, tri-slice out ----------------
// Row-local chain; t2 never leaves LDS. 512 thr / 8 waves, 32 rows/block.
__global__ void __launch_bounds__(512) mlp_phi_kernel(
    const float* __restrict__ x,
    const short* __restrict__ W1h, const short* __restrict__ W1l, const float* __restrict__ b1,
    const short* __restrict__ W2h, const short* __restrict__ W2l, const float* __restrict__ b2,
    float* __restrict__ C0, float* __restrict__ C1, float* __restrict__ C2, int M) {
  __shared__ short sm[4 * 32 * 136];   // XH | XL | TH | TL
  #define XH_(r,c) sm[(r)*136 + (c)]
  #define XL_(r,c) sm[4352 + (r)*136 + (c)]
  #define TH_(r,c) sm[8704 + (r)*136 + (c)]
  #define TL_(r,c) sm[13056 + (r)*136 + (c)]
  int tid = threadIdx.x;
  long r0 = (long)blockIdx.x * 32;
  #pragma unroll
  for (int i = 0; i < 2; i++) {
    int lin = i*512 + tid;
    int r = lin >> 5, c4 = lin & 31;
    long row = r0 + r; if (row >= M) row = M - 1;
    float4 f = *(const float4*)(x + row*128 + c4*4);
    split_store4(f, &XH_(r, c4*4), &XL_(r, c4*4));
  }
  __syncthreads();
  int lane = tid & 63, wv = tid >> 6;   // wv 0..7
  int l15 = lane & 15, q = lane >> 4;
  // GEMM1: t2 = silu(x@Wm1 + b1); wave w owns cols w*16+l15
  {
    int n = wv*16 + l15;
    v4f acc[2] = {};
    #pragma unroll
    for (int s = 0; s < 4; s++) {
      v8s bh = *(const v8s*)(W1h + (long)n*128 + s*32 + q*8);
      v8s bl = *(const v8s*)(W1l + (long)n*128 + s*32 + q*8);
      #pragma unroll
      for (int mt = 0; mt < 2; mt++) {
        v8s ah = *(const v8s*)&XH_(mt*16 + l15, s*32 + q*8);
        v8s al = *(const v8s*)&XL_(mt*16 + l15, s*32 + q*8);
        MFMA3(acc[mt], ah, al, bh, bl);
      }
    }
    float bb = b1[n];
    #pragma unroll
    for (int mt = 0; mt < 2; mt++)
      #pragma unroll
      for (int i = 0; i < 4; i++) {
        short h, l;
        split2(silu_f(acc[mt][i] + bb), h, l);
        TH_(mt*16 + q*4 + i, n) = h;
        TL_(mt*16 + q*4 + i, n) = l;
      }
  }
  __syncthreads();
  // GEMM2: phi = t2@Wm2 + b2 (384 cols; wave w -> n-tiles w*3..w*3+2)
  v4f acc[2][3] = {};
  #pragma unroll
  for (int s = 0; s < 4; s++) {
    v8s ah[2], al[2];
    #pragma unroll
    for (int mt = 0; mt < 2; mt++) {
      ah[mt] = *(const v8s*)&TH_(mt*16 + l15, s*32 + q*8);
      al[mt] = *(const v8s*)&TL_(mt*16 + l15, s*32 + q*8);
    }
    #pragma unroll
    for (int j = 0; j < 3; j++) {
      int n = (wv*3 + j)*16 + l15;
      v8s bh = *(const v8s*)(W2h + (long)n*128 + s*32 + q*8);
      v8s bl = *(const v8s*)(W2l + (long)n*128 + s*32 + q*8);
      #pragma unroll
      for (int mt = 0; mt < 2; mt++) { MFMA3(acc[mt][j], ah[mt], al[mt], bh, bl); }
    }
  }
  #pragma unroll
  for (int j = 0; j < 3; j++) {
    int n = (wv*3 + j)*16 + l15;
    int sl = n >> 7, col = n & 127;
    float* C = (sl == 0) ? C0 : (sl == 1) ? C1 : C2;
    float bb = b2[n];
    #pragma unroll
    for (int mt = 0; mt < 2; mt++)
      #pragma unroll
      for (int i = 0; i < 4; i++) {
        long row = r0 + mt*16 + q*4 + i;
        if (row < M) C[row*128 + col] = acc[mt][j][i] + bb;
      }
  }
  #undef XH_
  #undef XL_
  #undef TH_
  #undef TL_
}

// ---------------- FUSED message pass + Uv/Vv/Vn/s + a-MLP + update (muva) ----------------
// 16 nodes/block, 512 threads. Edge sweep (edge-balanced node partition) -> x_new fp32 /
// v_new bf16-hi/lo in LDS; MFMA phases read pre-split pairs (no per-wave SPLIT8).
__global__ void __launch_bounds__(512) muva_kernel(
    const float* __restrict__ phi0, const float* __restrict__ phi1,
    const float* __restrict__ phi2, const float* __restrict__ vA,
    float* __restrict__ vB, float* __restrict__ x,
    const int* __restrict__ srcs, const float4* __restrict__ eg1,
    const float4* __restrict__ eg2, const int* __restrict__ indptr,
    const float* __restrict__ Wf_l, const float* __restrict__ bf_l,
    const short* __restrict__ Uth, const short* __restrict__ Utl,
    const short* __restrict__ Vth, const short* __restrict__ Vtl,
    const short* __restrict__ W1h, const short* __restrict__ W1l, const float* __restrict__ b1,
    const short* __restrict__ W2h, const short* __restrict__ W2l, const float* __restrict__ b2) {
  __shared__ short svn[13056];     // VNH[48][136] | VNL ; overlaid by CATH/CATL/T2H/T2L
  __shared__ float xnf[16*136];    // XN fp32 (lives whole kernel)
  __shared__ int bnd[5];
  #define VNH(r,c)  svn[(r)*136 + (c)]
  #define VNL(r,c)  svn[6528 + (r)*136 + (c)]
  #define CATH(r,c) svn[(r)*264 + (c)]
  #define CATL(r,c) svn[4224 + (r)*264 + (c)]
  #define T2H(r,c)  svn[8448 + (r)*136 + (c)]
  #define T2L(r,c)  svn[10624 + (r)*136 + (c)]
  #define XN(r,c)   xnf[(r)*136 + (c)]
  const long NND = (long)NN*DD;
  int tid = threadIdx.x;
  long nb = (long)blockIdx.x * 16;
  // edge-balanced partition of the 16 nodes into 4 contiguous group ranges
  if (tid == 0) {
    int base = indptr[nb];
    int tot = indptr[nb + 16] - base;
    bnd[0] = 0;
    int g = 1;
    for (int i = 1; i <= 16 && g < 4; i++) {
      int pre = indptr[nb + i] - base;
      while (g < 4 && 4*pre >= g*tot) bnd[g++] = i;
    }
    while (g < 4) bnd[g++] = 16;
    bnd[4] = 16;
  }
  __syncthreads();
  // ---- phase E: edge sweep. group g = tid>>7 handles nodes [bnd[g], bnd[g+1]) ----
  {
    int g = tid >> 7, d = tid & 127;
    float wf0[NB_], wf1[NB_], wf2[NB_];
    #pragma unroll
    for (int k = 0; k < NB_; k++) {
      wf0[k] = Wf_l[k*D3 + d];
      wf1[k] = Wf_l[k*D3 + DD + d];
      wf2[k] = Wf_l[k*D3 + 2*DD + d];
    }
    float bf0 = bf_l[d], bf1 = bf_l[DD + d], bf2 = bf_l[2*DD + d];
    for (int nr = bnd[g]; nr < bnd[g+1]; nr++) {
      long n = nb + nr;
      int t = indptr[n], end = indptr[n+1];
      float xacc = 0.f, a0 = 0.f, a1 = 0.f, a2 = 0.f;
      float4 g1C = {}, g2C = {};
      float p0C = 0.f, p1C = 0.f, p2C = 0.f, w0C = 0.f, w1C = 0.f, w2C = 0.f;
      if (t < end) {
        int s0 = srcs[t]; g1C = eg1[t]; g2C = eg2[t];
        long b = (long)s0*DD + d;
        p0C = phi0[b]; p1C = phi1[b]; p2C = phi2[b];
        w0C = vA[b]; w1C = vA[NND + b]; w2C = vA[2*NND + b];
      }
      for (; t < end; t++) {
        float4 gg = g1C, dv = g2C;
        float p0 = p0C, p1 = p1C, p2 = p2C, w0 = w0C, w1 = w1C, w2 = w2C;
        if (t + 1 < end) {
          int sN = srcs[t+1]; g1C = eg1[t+1]; g2C = eg2[t+1];
          long b = (long)sN*DD + d;
          p0C = phi0[b]; p1C = phi1[b]; p2C = phi2[b];
          w0C = vA[b]; w1C = vA[NND + b]; w2C = vA[2*NND + b];
        }
        float c2 = 2.0f * gg.y;
        float rkm1 = 0.f, rk = gg.x, dot0 = 0.f, dot1 = 0.f, dot2 = 0.f;
        #pragma unroll
        for (int k = 0; k < NB_; k++) {
          dot0 = fmaf(rk, wf0[k], dot0);
          dot1 = fmaf(rk, wf1[k], dot1);
          dot2 = fmaf(rk, wf2[k], dot2);
          float rn = fmaf(c2, rk, -rkm1);
          rkm1 = rk; rk = rn;
        }
        xacc = fmaf(p0, bf0*gg.z + gg.w*dot0, xacc);
        float m1 = p1 * (bf1*gg.z + gg.w*dot1);
        float m2 = p2 * (bf2*gg.z + gg.w*dot2);
        a0 = fmaf(m1, dv.x, fmaf(m2, w0, a0));
        a1 = fmaf(m1, dv.y, fmaf(m2, w1, a1));
        a2 = fmaf(m1, dv.z, fmaf(m2, w2, a2));
      }
      long b = n*DD + d;
      XN(nr, d) = x[b] + xacc;
      short h, l;
      split2(vA[b] + a0, h, l);          VNH(nr, d) = h;      VNL(nr, d) = l;
      split2(vA[NND + b] + a1, h, l);    VNH(16+nr, d) = h;   VNL(16+nr, d) = l;
      split2(vA[2*NND + b] + a2, h, l);  VNH(32+nr, d) = h;   VNL(32+nr, d) = l;
    }
  }
  __syncthreads();
  int lane = tid & 63, wv = tid >> 6;   // wv 0..7
  int l15 = lane & 15, q = lane >> 4;
  int d = wv*16 + l15;                  // this wave's column slice
  // ---- phase 1: U & V projections for column-slice d (pre-split A pairs) ----
  v4f aU[3] = {}, aV[3] = {};
  #pragma unroll
  for (int s = 0; s < 4; s++) {
    long boff = (long)d*128 + s*32 + q*8;
    v8s buh = *(const v8s*)(Uth + boff);
    v8s bul = *(const v8s*)(Utl + boff);
    v8s bvh = *(const v8s*)(Vth + boff);
    v8s bvl = *(const v8s*)(Vtl + boff);
    #pragma unroll
    for (int c = 0; c < 3; c++) {
      v8s ah = *(const v8s*)&VNH(c*16 + l15, s*32 + q*8);
      v8s al = *(const v8s*)&VNL(c*16 + l15, s*32 + q*8);
      MFMA3(aU[c], ah, al, buh, bul);
      MFMA3(aV[c], ah, al, bvh, bvl);
    }
  }
  float sreg[4], vn2[4];
  #pragma unroll
  for (int i = 0; i < 4; i++) {
    sreg[i] = aU[0][i]*aV[0][i] + aU[1][i]*aV[1][i] + aU[2][i]*aV[2][i];
    vn2[i]  = aV[0][i]*aV[0][i] + aV[1][i]*aV[1][i] + aV[2][i]*aV[2][i];
  }
  // capture vold (v_new, reconstructed) before the cat/t2 overlay destroys VN
  float vold[4][3];
  #pragma unroll
  for (int i = 0; i < 4; i++)
    #pragma unroll
    for (int c = 0; c < 3; c++)
      vold[i][c] = bf2f(VNH(c*16 + q*4 + i, d)) + bf2f(VNL(c*16 + q*4 + i, d));
  __syncthreads();   // all reads of VN complete
  // ---- build cat = [x_new | Vn] as hi/lo pairs (split once) ----
  {
    int r = tid >> 5, c4 = tid & 31;   // 512 tasks: 16 rows x 32 float4-chunks
    float4 f = *(const float4*)&XN(r, c4*4);
    split_store4(f, &CATH(r, c4*4), &CATL(r, c4*4));
  }
  #pragma unroll
  for (int i = 0; i < 4; i++) {
    short h, l;
    split2(sqrtf(vn2[i] + 1e-8f), h, l);
    CATH(q*4 + i, 128 + d) = h;
    CATL(q*4 + i, 128 + d) = l;
  }
  __syncthreads();
  // ---- GEMM1: t2[:, d] = silu(cat @ Wu1 + b1), K=256 ----
  {
    v4f acc = {};
    #pragma unroll
    for (int s = 0; s < 8; s++) {
      v8s ah = *(const v8s*)&CATH(l15, s*32 + q*8);
      v8s al = *(const v8s*)&CATL(l15, s*32 + q*8);
      v8s bh = *(const v8s*)(W1h + (long)d*256 + s*32 + q*8);
      v8s bl = *(const v8s*)(W1l + (long)d*256 + s*32 + q*8);
      MFMA3(acc, ah, al, bh, bl);
    }
    float bb = b1[d];
    #pragma unroll
    for (int i = 0; i < 4; i++) {
      short h, l;
      split2(silu_f(acc[i] + bb), h, l);
      T2H(q*4 + i, d) = h;
      T2L(q*4 + i, d) = l;
    }
  }
  __syncthreads();
  // ---- GEMM2 + epilogue ----
  {
    v4f acc[3] = {};
    #pragma unroll
    for (int s = 0; s < 4; s++) {
      v8s ah = *(const v8s*)&T2H(l15, s*32 + q*8);
      v8s al = *(const v8s*)&T2L(l15, s*32 + q*8);
      #pragma unroll
      for (int g = 0; g < 3; g++) {
        int n = g*128 + d;                 // avv: d, asv: 128+d, ass: 256+d
        v8s bh = *(const v8s*)(W2h + (long)n*128 + s*32 + q*8);
        v8s bl = *(const v8s*)(W2l + (long)n*128 + s*32 + q*8);
        MFMA3(acc[g], ah, al, bh, bl);
      }
    }
    float bavv = b2[d], basv = b2[128 + d], bass = b2[256 + d];
    #pragma unroll
    for (int i = 0; i < 4; i++) {
      int lr = q*4 + i;
      long row = nb + lr;
      float avv = acc[0][i] + bavv;
      float asv = acc[1][i] + basv;
      float ass = acc[2][i] + bass;
      x[row*DD + d] = XN(lr, d) + ass + asv * sreg[i];
      #pragma unroll
      for (int c = 0; c < 3; c++)
        vB[(long)c*NND + row*DD + d] = fmaf(avv, aU[c][i], vold[i][c]);
    }
  }
  #undef VNH
  #undef VNL
  #undef CATH
  #undef CATL
  #undef T2H
  #undef T2L
  #undef XN
}

// ---------------- output head + segment sum: 4 nodes/block, LDS-staged x ----------------
__global__ void __launch_bounds__(256) out_kernel(
    const float* __restrict__ x, const float* __restrict__ Wo1,
    const float* __restrict__ bo1, const float* __restrict__ Wo2,
    const float* __restrict__ bo2, const int* __restrict__ batch,
    float* __restrict__ out) {
  __shared__ float xs[4][132];
  int tid = threadIdx.x;
  long n0 = (long)blockIdx.x * 4;
  if (tid < 128) {
    int r = tid >> 5, c4 = tid & 31;
    *(float4*)&xs[r][c4*4] = *(const float4*)(x + (n0 + r)*128 + c4*4);
  }
  __syncthreads();
  int wv = tid >> 6, t = tid & 63;
  float acc = bo1[t];
  #pragma unroll 16
  for (int k = 0; k < DD; k++) acc = fmaf(xs[wv][k], Wo1[k*HH + t], acc);
  float val = silu_f(acc) * Wo2[t];
  #pragma unroll
  for (int off = 32; off > 0; off >>= 1) val += __shfl_down(val, off);
  if (t == 0) atomicAdd(&out[batch[n0 + wv]], val + bo2[0]);
}

// ---------------- launcher ----------------
extern "C" void kernel_launch(void* const* d_in, const int* in_sizes, int n_in,
                              void* d_out, int out_size, void* d_ws, size_t ws_size,
                              hipStream_t stream) {
  const int*   at_no = (const int*)d_in[0];
  const float* pos   = (const float*)d_in[1];
  const int*   ei    = (const int*)d_in[2];
  const int*   batch = (const int*)d_in[3];
  const float* emb   = (const float*)d_in[4];
  const float* Wf    = (const float*)d_in[5];
  const float* bfp   = (const float*)d_in[6];
  const float* Wm1   = (const float*)d_in[7];
  const float* bm1   = (const float*)d_in[8];
  const float* Wm2   = (const float*)d_in[9];
  const float* bm2   = (const float*)d_in[10];
  const float* U     = (const float*)d_in[11];
  const float* V     = (const float*)d_in[12];
  const float* Wu1   = (const float*)d_in[13];
  const float* bu1   = (const float*)d_in[14];
  const float* Wu2   = (const float*)d_in[15];
  const float* bu2   = (const float*)d_in[16];
  const float* Wo1   = (const float*)d_in[17];
  const float* bo1   = (const float*)d_in[18];
  const float* Wo2   = (const float*)d_in[19];
  const float* bo2   = (const float*)d_in[20];
  float* out = (float*)d_out;

  char* w = (char*)d_ws;
  auto alloc = [&](size_t bytes) -> void* {
    void* p = (void*)w;
    w += (bytes + 255) & ~(size_t)255;
    return p;
  };
  float*  x      = (float*)alloc(sizeof(float)*(size_t)NN*DD);
  float*  v_a    = (float*)alloc(sizeof(float)*(size_t)NN*D3);   // plane layout [3][NN][DD]
  float*  v_b    = (float*)alloc(sizeof(float)*(size_t)NN*D3);
  float*  t1     = (float*)alloc(sizeof(float)*(size_t)NN*DD);   // phi slice 2
  float*  phiS   = (float*)alloc(sizeof(float)*(size_t)NN*DD);   // phi slice 1
  float*  phi0   = (float*)alloc(sizeof(float)*(size_t)NN*DD);   // phi slice 0
  short*  wbh    = (short*)alloc(sizeof(short)*(size_t)3*LSZ);   // bf16-hi weights
  short*  wbl    = (short*)alloc(sizeof(short)*(size_t)3*LSZ);   // bf16-lo weights
  int*    srcs   = (int*)alloc(sizeof(int)*(size_t)ECAP);
  float4* eg1    = (float4*)alloc(sizeof(float4)*(size_t)ECAP);
  float4* eg2    = (float4*)alloc(sizeof(float4)*(size_t)ECAP);
  int*    indptr = (int*)alloc(sizeof(int)*((size_t)NN+1));
  int*    counts = (int*)alloc(sizeof(int)*(size_t)NN);

  if ((size_t)(w - (char*)d_ws) > ws_size) {   // diagnostic guard: zeros => ws too small
    zero_f_kernel<<<2, 256, 0, stream>>>(out, NG_);
    return;
  }

  zero_f_kernel<<<2048, 256, 0, stream>>>(v_a, (long)NN*D3);
  zero_f_kernel<<<2, 256, 0, stream>>>(out, NG_);
  zero_i_kernel<<<64, 256, 0, stream>>>(counts, NN);
  init_x_kernel<<<(NN*DD + 255)/256, 256, 0, stream>>>(at_no, emb, x);
  prep_w_kernel<<<(3*LSZ + 255)/256, 256, 0, stream>>>(Wm1, Wm2, U, V, Wu1, Wu2, wbh, wbl);
  hist_kernel<<<(NE + 255)/256, 256, 0, stream>>>(ei, pos, counts);
  scan_kernel<<<1, 1024, 0, stream>>>(counts, indptr, NN);
  zero_i_kernel<<<64, 256, 0, stream>>>(counts, NN);
  fill_kernel<<<(NE + 255)/256, 256, 0, stream>>>(ei, pos, indptr, counts, srcs, eg1, eg2);

  const int MB = (NN + 31) / 32;    // 1563
  float* vcur = v_a;
  float* vnext = v_b;
  for (int l = 0; l < 3; l++) {
    const float* Wf_l  = Wf  + (size_t)l*NB_*D3;
    const float* bf_l  = bfp + (size_t)l*D3;
    const float* bm1_l = bm1 + (size_t)l*DD;
    const float* bm2_l = bm2 + (size_t)l*D3;
    const float* bu1_l = bu1 + (size_t)l*DD;
    const float* bu2_l = bu2 + (size_t)l*D3;
    const short* Lh = wbh + (size_t)l*LSZ;
    const short* Ll = wbl + (size_t)l*LSZ;
    const short* Wm1h = Lh,          *Wm1L = Ll;
    const short* Wm2h = Lh + 16384,  *Wm2L = Ll + 16384;
    const short* Uh   = Lh + 65536,  *UL   = Ll + 65536;
    const short* Vh   = Lh + 81920,  *VL   = Ll + 81920;
    const short* Wu1h = Lh + 98304,  *Wu1L = Ll + 98304;
    const short* Wu2h = Lh + 131072, *Wu2L = Ll + 131072;

    // fused node-MLP: x -> t2 (LDS) -> phi slices {phi0, phiS, t1}
    mlp_phi_kernel<<<MB, 512, 0, stream>>>(x, Wm1h, Wm1L, bm1_l, Wm2h, Wm2L, bm2_l,
                                           phi0, phiS, t1, NN);
    // fused: edge sweep + U/V proj + a-MLP + x,v update (x_new/v_new stay in LDS)
    muva_kernel<<<NN/16, 512, 0, stream>>>(phi0, phiS, t1, vcur, vnext, x,
                                           srcs, eg1, eg2, indptr, Wf_l, bf_l,
                                           Uh, UL, Vh, VL,
                                           Wu1h, Wu1L, bu1_l, Wu2h, Wu2L, bu2_l);

    float* tmp = vcur; vcur = vnext; vnext = tmp;
  }

  out_kernel<<<NN/4, 256, 0, stream>>>(x, Wo1, bo1, Wo2, bo2, batch, out);

  (void)in_sizes; (void)n_in; (void)out_size; (void)ws_size;
}

// Round 16
// 1426.943 us; speedup vs baseline: 1.0447x; 1.0447x over previous
//
#include <hip/hip_runtime.h>
#include <math.h>

#define NN 50000
#define NE 600000
#define ECAP 230000  // capacity for filtered edges (actual ~175K)
#define DD 128
#define D3 384
#define NB_ 20
#define HH 64
#define NG_ 512
#define LSZ 180224   // shorts per layer of transposed-bf16 weights

typedef short v8s __attribute__((ext_vector_type(8)));
typedef short v4sh __attribute__((ext_vector_type(4)));
typedef float v4f __attribute__((ext_vector_type(4)));

__device__ __forceinline__ float silu_f(float z) { return z / (1.0f + expf(-z)); }

__device__ __forceinline__ short f2bf(float f) {
  unsigned u = __float_as_uint(f);
  u += 0x7FFF + ((u >> 16) & 1);          // RNE
  return (short)(u >> 16);
}
__device__ __forceinline__ float bf2f(short s) {
  return __uint_as_float(((unsigned)(unsigned short)s) << 16);
}
__device__ __forceinline__ void split2(float x, short& h, short& l) {
  h = f2bf(x);
  l = f2bf(x - bf2f(h));
}
#define SPLIT8(f0, f1, ah, al) { short h,l; \
  split2(f0.x,h,l); ah[0]=h; al[0]=l;  split2(f0.y,h,l); ah[1]=h; al[1]=l; \
  split2(f0.z,h,l); ah[2]=h; al[2]=l;  split2(f0.w,h,l); ah[3]=h; al[3]=l; \
  split2(f1.x,h,l); ah[4]=h; al[4]=l;  split2(f1.y,h,l); ah[5]=h; al[5]=l; \
  split2(f1.z,h,l); ah[6]=h; al[6]=l;  split2(f1.w,h,l); ah[7]=h; al[7]=l; }
// split a float4 and store hi/lo as short4 (8B LDS stores)
__device__ __forceinline__ void split_store4(float4 f, short* hp, short* lp) {
  short h0,l0,h1,l1,h2,l2,h3,l3;
  split2(f.x,h0,l0); split2(f.y,h1,l1); split2(f.z,h2,l2); split2(f.w,h3,l3);
  v4sh hv = {h0,h1,h2,h3}, lv = {l0,l1,l2,l3};
  *(v4sh*)hp = hv; *(v4sh*)lp = lv;
}
// 3-term Markidis split: acc += ah@bh + al@bh + ah@bl   (proven: absmax 4.3e9)
#define MFMA3(acc, ah, al, bh, bl) \
  acc = __builtin_amdgcn_mfma_f32_16x16x32_bf16(ah, bh, acc, 0, 0, 0); \
  acc = __builtin_amdgcn_mfma_f32_16x16x32_bf16(al, bh, acc, 0, 0, 0); \
  acc = __builtin_amdgcn_mfma_f32_16x16x32_bf16(ah, bl, acc, 0, 0, 0);

// ---------------- utility ----------------
__global__ void zero_f_kernel(float* __restrict__ p, long n) {
  long i = (long)blockIdx.x * blockDim.x + threadIdx.x;
  long s = (long)gridDim.x * blockDim.x;
  for (; i < n; i += s) p[i] = 0.0f;
}

__global__ void zero_i_kernel(int* __restrict__ p, long n) {
  long i = (long)blockIdx.x * blockDim.x + threadIdx.x;
  long s = (long)gridDim.x * blockDim.x;
  for (; i < n; i += s) p[i] = 0;
}

__global__ void init_x_kernel(const int* __restrict__ at_no, const float* __restrict__ emb,
                              float* __restrict__ x) {
  int i = blockIdx.x * blockDim.x + threadIdx.x;
  if (i >= NN * DD) return;
  x[i] = emb[at_no[i >> 7] * DD + (i & 127)];
}

// ---------------- weight prep: fp32 [K][N] -> transposed bf16 hi/lo [N][K] ----------------
__global__ void prep_w_kernel(const float* __restrict__ Wm1, const float* __restrict__ Wm2,
                              const float* __restrict__ U, const float* __restrict__ V,
                              const float* __restrict__ Wu1, const float* __restrict__ Wu2,
                              short* __restrict__ hi, short* __restrict__ lo) {
  int idx = blockIdx.x * 256 + threadIdx.x;
  if (idx >= 3 * LSZ) return;
  int l = idx / LSZ, r = idx % LSZ;
  const float* src; int K, N, nk;
  if (r < 16384)       { src = Wm1 + (size_t)l*16384; K = 128; N = 128; nk = r; }
  else if (r < 65536)  { src = Wm2 + (size_t)l*49152; K = 128; N = 384; nk = r - 16384; }
  else if (r < 81920)  { src = U   + (size_t)l*16384; K = 128; N = 128; nk = r - 65536; }
  else if (r < 98304)  { src = V   + (size_t)l*16384; K = 128; N = 128; nk = r - 81920; }
  else if (r < 131072) { src = Wu1 + (size_t)l*32768; K = 256; N = 128; nk = r - 98304; }
  else                 { src = Wu2 + (size_t)l*49152; K = 128; N = 384; nk = r - 131072; }
  int n = nk / K, k = nk - n * K;
  float xx = src[(size_t)k * N + n];
  short h = f2bf(xx);
  hi[idx] = h;
  lo[idx] = f2bf(xx - bf2f(h));
}

// ---------------- CSR build (dst-sorted), filtering dist>=CUTOFF edges ----------------
__global__ void hist_kernel(const int* __restrict__ ei, const float* __restrict__ pos,
                            int* __restrict__ counts) {
  int e = blockIdx.x * blockDim.x + threadIdx.x;
  if (e >= NE) return;
  int s = ei[e], d = ei[NE + e];
  float dx = pos[3*d]   - pos[3*s];
  float dy = pos[3*d+1] - pos[3*s+1];
  float dz = pos[3*d+2] - pos[3*s+2];
  float d2 = dx*dx + dy*dy + dz*dz + 1e-12f;
  if (d2 < 25.0f) atomicAdd(&counts[d], 1);
}

__global__ void scan_kernel(const int* __restrict__ counts, int* __restrict__ indptr, int n) {
  __shared__ int sm[1024];
  __shared__ int carry_s;
  if (threadIdx.x == 0) carry_s = 0;
  __syncthreads();
  for (int start = 0; start < n; start += 1024) {
    int i = start + (int)threadIdx.x;
    int val = (i < n) ? counts[i] : 0;
    sm[threadIdx.x] = val;
    __syncthreads();
    for (int off = 1; off < 1024; off <<= 1) {
      int t = (threadIdx.x >= (unsigned)off) ? sm[threadIdx.x - off] : 0;
      __syncthreads();
      sm[threadIdx.x] += t;
      __syncthreads();
    }
    int c = carry_s;
    if (i < n) indptr[i] = c + sm[threadIdx.x] - val;
    __syncthreads();
    if (threadIdx.x == 0) carry_s = c + sm[1023];
    __syncthreads();
  }
  if (threadIdx.x == 0) indptr[n] = carry_s;
}

__global__ void fill_kernel(const int* __restrict__ ei, const float* __restrict__ pos,
                            const int* __restrict__ indptr, int* __restrict__ cursor,
                            int* __restrict__ srcs, float4* __restrict__ eg1,
                            float4* __restrict__ eg2) {
  int e = blockIdx.x * blockDim.x + threadIdx.x;
  if (e >= NE) return;
  int s = ei[e], d = ei[NE + e];
  float dx = pos[3*d]   - pos[3*s];
  float dy = pos[3*d+1] - pos[3*s+1];
  float dz = pos[3*d+2] - pos[3*s+2];
  float d2 = dx*dx + dy*dy + dz*dz + 1e-12f;
  if (d2 < 25.0f) {
    int p = atomicAdd(&cursor[d], 1);
    int slot = indptr[d] + p;
    float dist = sqrtf(d2);
    float inv = 1.0f / dist;
    float wang = 0.62831853071795864769f * dist;   // pi*dist/CUTOFF
    float s1 = __sinf(wang), c1 = __cosf(wang);
    float fc = 0.5f * (c1 + 1.0f);
    srcs[slot] = s;
    eg1[slot] = make_float4(s1, c1, fc, fc * inv);
    eg2[slot] = make_float4(dx * inv, dy * inv, dz * inv, 0.0f);
  }
}

// ---------------- fused node MLP: phi = silu(x@Wm1+b1)@Wm2+b2, tri-slice out ----------------
// Row-local chain; t2 never leaves LDS. 512 thr / 8 waves, 32 rows/block.
__global__ void __launch_bounds__(512) mlp_phi_kernel(
    const float* __restrict__ x,
    const short* __restrict__ W1h, const short* __restrict__ W1l, const float* __restrict__ b1,
    const short* __restrict__ W2h, const short* __restrict__ W2l, const float* __restrict__ b2,
    float* __restrict__ C0, float* __restrict__ C1, float* __restrict__ C2, int M) {
  __shared__ short sm[4 * 32 * 136];   // XH | XL | TH | TL
  #define XH_(r,c) sm[(r)*136 + (c)]
  #define XL_(r,c) sm[4352 + (r)*136 + (c)]
  #define TH_(r,c) sm[8704 + (r)*136 + (c)]
  #define TL_(r,c) sm[13056 + (r)*136 + (c)]
  int tid = threadIdx.x;
  long r0 = (long)blockIdx.x * 32;
  #pragma unroll
  for (int i = 0; i < 2; i++) {
    int lin = i*512 + tid;
    int r = lin >> 5, c4 = lin & 31;
    long row = r0 + r; if (row >= M) row = M - 1;
    float4 f = *(const float4*)(x + row*128 + c4*4);
    split_store4(f, &XH_(r, c4*4), &XL_(r, c4*4));
  }
  __syncthreads();
  int lane = tid & 63, wv = tid >> 6;   // wv 0..7
  int l15 = lane & 15, q = lane >> 4;
  // GEMM1: t2 = silu(x@Wm1 + b1); wave w owns cols w*16+l15
  {
    int n = wv*16 + l15;
    v4f acc[2] = {};
    #pragma unroll
    for (int s = 0; s < 4; s++) {
      v8s bh = *(const v8s*)(W1h + (long)n*128 + s*32 + q*8);
      v8s bl = *(const v8s*)(W1l + (long)n*128 + s*32 + q*8);
      #pragma unroll
      for (int mt = 0; mt < 2; mt++) {
        v8s ah = *(const v8s*)&XH_(mt*16 + l15, s*32 + q*8);
        v8s al = *(const v8s*)&XL_(mt*16 + l15, s*32 + q*8);
        MFMA3(acc[mt], ah, al, bh, bl);
      }
    }
    float bb = b1[n];
    #pragma unroll
    for (int mt = 0; mt < 2; mt++)
      #pragma unroll
      for (int i = 0; i < 4; i++) {
        short h, l;
        split2(silu_f(acc[mt][i] + bb), h, l);
        TH_(mt*16 + q*4 + i, n) = h;
        TL_(mt*16 + q*4 + i, n) = l;
      }
  }
  __syncthreads();
  // GEMM2: phi = t2@Wm2 + b2 (384 cols; wave w -> n-tiles w*3..w*3+2)
  v4f acc[2][3] = {};
  #pragma unroll
  for (int s = 0; s < 4; s++) {
    v8s ah[2], al[2];
    #pragma unroll
    for (int mt = 0; mt < 2; mt++) {
      ah[mt] = *(const v8s*)&TH_(mt*16 + l15, s*32 + q*8);
      al[mt] = *(const v8s*)&TL_(mt*16 + l15, s*32 + q*8);
    }
    #pragma unroll
    for (int j = 0; j < 3; j++) {
      int n = (wv*3 + j)*16 + l15;
      v8s bh = *(const v8s*)(W2h + (long)n*128 + s*32 + q*8);
      v8s bl = *(const v8s*)(W2l + (long)n*128 + s*32 + q*8);
      #pragma unroll
      for (int mt = 0; mt < 2; mt++) { MFMA3(acc[mt][j], ah[mt], al[mt], bh, bl); }
    }
  }
  #pragma unroll
  for (int j = 0; j < 3; j++) {
    int n = (wv*3 + j)*16 + l15;
    int sl = n >> 7, col = n & 127;
    float* C = (sl == 0) ? C0 : (sl == 1) ? C1 : C2;
    float bb = b2[n];
    #pragma unroll
    for (int mt = 0; mt < 2; mt++)
      #pragma unroll
      for (int i = 0; i < 4; i++) {
        long row = r0 + mt*16 + q*4 + i;
        if (row < M) C[row*128 + col] = acc[mt][j][i] + bb;
      }
  }
  #undef XH_
  #undef XL_
  #undef TH_
  #undef TL_
}

// ---------------- FUSED message pass + Uv/Vv/Vn/s + a-MLP + update (muva, R14 best) ----------------
// 16 nodes/block, 512 threads. Edge sweep -> x_new/v_new in LDS (never globalized);
// then U/V projections (wave w owns column slice d=w*16+l15), GEMM1, GEMM2, epilogue.
// fp32 LDS staging + per-wave SPLIT8 (measured faster than split-once in the sweep).
__global__ void __launch_bounds__(512) muva_kernel(
    const float* __restrict__ phi0, const float* __restrict__ phi1,
    const float* __restrict__ phi2, const float* __restrict__ vA,
    float* __restrict__ vB, float* __restrict__ x,
    const int* __restrict__ srcs, const float4* __restrict__ eg1,
    const float4* __restrict__ eg2, const int* __restrict__ indptr,
    const float* __restrict__ Wf_l, const float* __restrict__ bf_l,
    const short* __restrict__ Uth, const short* __restrict__ Utl,
    const short* __restrict__ Vth, const short* __restrict__ Vtl,
    const short* __restrict__ W1h, const short* __restrict__ W1l, const float* __restrict__ b1,
    const short* __restrict__ W2h, const short* __restrict__ W2l, const float* __restrict__ b2) {
  __shared__ float smem[8896];   // 35584 B
  // region A [0,6720): v_new [48][140]; later overlaid by cat[16][276] | t2[16][140]
  // region B [6720,8896): x_new [16][136]
  #define VN(r,c)  smem[(r)*140 + (c)]
  #define XN(r,c)  smem[6720 + (r)*136 + (c)]
  #define CAT(r,c) smem[(r)*276 + (c)]
  #define T2(r,c)  smem[4416 + (r)*140 + (c)]
  const long NND = (long)NN*DD;
  int tid = threadIdx.x;
  long nb = (long)blockIdx.x * 16;
  // ---- phase E: edge sweep. 4 groups x 128 d-lanes; group g handles nodes 4g..4g+3 ----
  {
    int g = tid >> 7, d = tid & 127;
    float wf0[NB_], wf1[NB_], wf2[NB_];
    #pragma unroll
    for (int k = 0; k < NB_; k++) {
      wf0[k] = Wf_l[k*D3 + d];
      wf1[k] = Wf_l[k*D3 + DD + d];
      wf2[k] = Wf_l[k*D3 + 2*DD + d];
    }
    float bf0 = bf_l[d], bf1 = bf_l[DD + d], bf2 = bf_l[2*DD + d];
    for (int j = 0; j < 4; j++) {
      int nr = 4*g + j;
      long n = nb + nr;
      int t = indptr[n], end = indptr[n+1];
      float xacc = 0.f, a0 = 0.f, a1 = 0.f, a2 = 0.f;
      float4 g1C = {}, g2C = {};
      float p0C = 0.f, p1C = 0.f, p2C = 0.f, w0C = 0.f, w1C = 0.f, w2C = 0.f;
      if (t < end) {
        int s0 = srcs[t]; g1C = eg1[t]; g2C = eg2[t];
        long b = (long)s0*DD + d;
        p0C = phi0[b]; p1C = phi1[b]; p2C = phi2[b];
        w0C = vA[b]; w1C = vA[NND + b]; w2C = vA[2*NND + b];
      }
      for (; t < end; t++) {
        float4 gg = g1C, dv = g2C;
        float p0 = p0C, p1 = p1C, p2 = p2C, w0 = w0C, w1 = w1C, w2 = w2C;
        if (t + 1 < end) {
          int sN = srcs[t+1]; g1C = eg1[t+1]; g2C = eg2[t+1];
          long b = (long)sN*DD + d;
          p0C = phi0[b]; p1C = phi1[b]; p2C = phi2[b];
          w0C = vA[b]; w1C = vA[NND + b]; w2C = vA[2*NND + b];
        }
        float c2 = 2.0f * gg.y;
        float rkm1 = 0.f, rk = gg.x, dot0 = 0.f, dot1 = 0.f, dot2 = 0.f;
        #pragma unroll
        for (int k = 0; k < NB_; k++) {
          dot0 = fmaf(rk, wf0[k], dot0);
          dot1 = fmaf(rk, wf1[k], dot1);
          dot2 = fmaf(rk, wf2[k], dot2);
          float rn = fmaf(c2, rk, -rkm1);
          rkm1 = rk; rk = rn;
        }
        xacc = fmaf(p0, bf0*gg.z + gg.w*dot0, xacc);
        float m1 = p1 * (bf1*gg.z + gg.w*dot1);
        float m2 = p2 * (bf2*gg.z + gg.w*dot2);
        a0 = fmaf(m1, dv.x, fmaf(m2, w0, a0));
        a1 = fmaf(m1, dv.y, fmaf(m2, w1, a1));
        a2 = fmaf(m1, dv.z, fmaf(m2, w2, a2));
      }
      long b = n*DD + d;
      XN(nr, d) = x[b] + xacc;
      VN(nr, d)      = vA[b]         + a0;   // channel 0 rows 0..15
      VN(16 + nr, d) = vA[NND + b]   + a1;   // channel 1 rows 16..31
      VN(32 + nr, d) = vA[2*NND + b] + a2;   // channel 2 rows 32..47
    }
  }
  __syncthreads();
  int lane = tid & 63, wv = tid >> 6;   // wv 0..7
  int l15 = lane & 15, q = lane >> 4;
  int d = wv*16 + l15;                  // this wave's column slice
  // ---- phase 1: U & V projections for column-slice d, per channel (split per-wave) ----
  v4f aU[3] = {}, aV[3] = {};
  #pragma unroll
  for (int s = 0; s < 4; s++) {
    long boff = (long)d*128 + s*32 + q*8;
    v8s buh = *(const v8s*)(Uth + boff);
    v8s bul = *(const v8s*)(Utl + boff);
    v8s bvh = *(const v8s*)(Vth + boff);
    v8s bvl = *(const v8s*)(Vtl + boff);
    #pragma unroll
    for (int c = 0; c < 3; c++) {
      float4 f0 = *(const float4*)&VN(c*16 + l15, s*32 + q*8);
      float4 f1 = *(const float4*)&VN(c*16 + l15, s*32 + q*8 + 4);
      v8s ah, al;
      SPLIT8(f0, f1, ah, al);
      MFMA3(aU[c], ah, al, buh, bul);
      MFMA3(aV[c], ah, al, bvh, bvl);
    }
  }
  float sreg[4], vn2[4];
  #pragma unroll
  for (int i = 0; i < 4; i++) {
    sreg[i] = aU[0][i]*aV[0][i] + aU[1][i]*aV[1][i] + aU[2][i]*aV[2][i];
    vn2[i]  = aV[0][i]*aV[0][i] + aV[1][i]*aV[1][i] + aV[2][i]*aV[2][i];
  }
  // capture vold (v_new) to registers before the cat/t2 overlay destroys VN
  float vold[4][3];
  #pragma unroll
  for (int i = 0; i < 4; i++)
    #pragma unroll
    for (int c = 0; c < 3; c++) vold[i][c] = VN(c*16 + q*4 + i, d);
  __syncthreads();   // all reads of VN complete
  // ---- build cat = [x_new | Vn] (fp32, overlays VN region) ----
  {
    int r = tid >> 5, c4 = tid & 31;   // 512 tasks: 16 rows x 32 float4-chunks
    *(float4*)&CAT(r, c4*4) = *(const float4*)&XN(r, c4*4);
  }
  #pragma unroll
  for (int i = 0; i < 4; i++)
    CAT(q*4 + i, 128 + d) = sqrtf(vn2[i] + 1e-8f);
  __syncthreads();
  // ---- GEMM1: t2[:, d] = silu(cat @ Wu1 + b1), K=256 ----
  {
    v4f acc = {};
    #pragma unroll
    for (int s = 0; s < 8; s++) {
      float4 f0 = *(const float4*)&CAT(l15, s*32 + q*8);
      float4 f1 = *(const float4*)&CAT(l15, s*32 + q*8 + 4);
      v8s ah, al;
      SPLIT8(f0, f1, ah, al);
      v8s bh = *(const v8s*)(W1h + (long)d*256 + s*32 + q*8);
      v8s bl = *(const v8s*)(W1l + (long)d*256 + s*32 + q*8);
      MFMA3(acc, ah, al, bh, bl);
    }
    float bb = b1[d];
    #pragma unroll
    for (int i = 0; i < 4; i++)
      T2(q*4 + i, d) = silu_f(acc[i] + bb);
  }
  __syncthreads();
  // ---- GEMM2 + epilogue ----
  {
    v4f acc[3] = {};
    #pragma unroll
    for (int s = 0; s < 4; s++) {
      float4 f0 = *(const float4*)&T2(l15, s*32 + q*8);
      float4 f1 = *(const float4*)&T2(l15, s*32 + q*8 + 4);
      v8s ah, al;
      SPLIT8(f0, f1, ah, al);
      #pragma unroll
      for (int g = 0; g < 3; g++) {
        int n = g*128 + d;                 // avv: d, asv: 128+d, ass: 256+d
        v8s bh = *(const v8s*)(W2h + (long)n*128 + s*32 + q*8);
        v8s bl = *(const v8s*)(W2l + (long)n*128 + s*32 + q*8);
        MFMA3(acc[g], ah, al, bh, bl);
      }
    }
    float bavv = b2[d], basv = b2[128 + d], bass = b2[256 + d];
    #pragma unroll
    for (int i = 0; i < 4; i++) {
      int lr = q*4 + i;
      long row = nb + lr;
      float avv = acc[0][i] + bavv;
      float asv = acc[1][i] + basv;
      float ass = acc[2][i] + bass;
      x[row*DD + d] = CAT(lr, d) + ass + asv * sreg[i];
      #pragma unroll
      for (int c = 0; c < 3; c++)
        vB[(long)c*NND + row*DD + d] = fmaf(avv, aU[c][i], vold[i][c]);
    }
  }
  #undef VN
  #undef XN
  #undef CAT
  #undef T2
}

// ---------------- output head + segment sum: 4 nodes/block, LDS-staged x ----------------
__global__ void __launch_bounds__(256) out_kernel(
    const float* __restrict__ x, const float* __restrict__ Wo1,
    const float* __restrict__ bo1, const float* __restrict__ Wo2,
    const float* __restrict__ bo2, const int* __restrict__ batch,
    float* __restrict__ out) {
  __shared__ float xs[4][132];
  int tid = threadIdx.x;
  long n0 = (long)blockIdx.x * 4;
  if (tid < 128) {
    int r = tid >> 5, c4 = tid & 31;
    *(float4*)&xs[r][c4*4] = *(const float4*)(x + (n0 + r)*128 + c4*4);
  }
  __syncthreads();
  int wv = tid >> 6, t = tid & 63;
  float acc = bo1[t];
  #pragma unroll 16
  for (int k = 0; k < DD; k++) acc = fmaf(xs[wv][k], Wo1[k*HH + t], acc);
  float val = silu_f(acc) * Wo2[t];
  #pragma unroll
  for (int off = 32; off > 0; off >>= 1) val += __shfl_down(val, off);
  if (t == 0) atomicAdd(&out[batch[n0 + wv]], val + bo2[0]);
}

// ---------------- launcher ----------------
extern "C" void kernel_launch(void* const* d_in, const int* in_sizes, int n_in,
                              void* d_out, int out_size, void* d_ws, size_t ws_size,
                              hipStream_t stream) {
  const int*   at_no = (const int*)d_in[0];
  const float* pos   = (const float*)d_in[1];
  const int*   ei    = (const int*)d_in[2];
  const int*   batch = (const int*)d_in[3];
  const float* emb   = (const float*)d_in[4];
  const float* Wf    = (const float*)d_in[5];
  const float* bfp   = (const float*)d_in[6];
  const float* Wm1   = (const float*)d_in[7];
  const float* bm1   = (const float*)d_in[8];
  const float* Wm2   = (const float*)d_in[9];
  const float* bm2   = (const float*)d_in[10];
  const float* U     = (const float*)d_in[11];
  const float* V     = (const float*)d_in[12];
  const float* Wu1   = (const float*)d_in[13];
  const float* bu1   = (const float*)d_in[14];
  const float* Wu2   = (const float*)d_in[15];
  const float* bu2   = (const float*)d_in[16];
  const float* Wo1   = (const float*)d_in[17];
  const float* bo1   = (const float*)d_in[18];
  const float* Wo2   = (const float*)d_in[19];
  const float* bo2   = (const float*)d_in[20];
  float* out = (float*)d_out;

  char* w = (char*)d_ws;
  auto alloc = [&](size_t bytes) -> void* {
    void* p = (void*)w;
    w += (bytes + 255) & ~(size_t)255;
    return p;
  };
  float*  x      = (float*)alloc(sizeof(float)*(size_t)NN*DD);
  float*  v_a    = (float*)alloc(sizeof(float)*(size_t)NN*D3);   // plane layout [3][NN][DD]
  float*  v_b    = (float*)alloc(sizeof(float)*(size_t)NN*D3);
  float*  t1     = (float*)alloc(sizeof(float)*(size_t)NN*DD);   // phi slice 2
  float*  phiS   = (float*)alloc(sizeof(float)*(size_t)NN*DD);   // phi slice 1
  float*  phi0   = (float*)alloc(sizeof(float)*(size_t)NN*DD);   // phi slice 0
  short*  wbh    = (short*)alloc(sizeof(short)*(size_t)3*LSZ);   // bf16-hi weights
  short*  wbl    = (short*)alloc(sizeof(short)*(size_t)3*LSZ);   // bf16-lo weights
  int*    srcs   = (int*)alloc(sizeof(int)*(size_t)ECAP);
  float4* eg1    = (float4*)alloc(sizeof(float4)*(size_t)ECAP);
  float4* eg2    = (float4*)alloc(sizeof(float4)*(size_t)ECAP);
  int*    indptr = (int*)alloc(sizeof(int)*((size_t)NN+1));
  int*    counts = (int*)alloc(sizeof(int)*(size_t)NN);

  if ((size_t)(w - (char*)d_ws) > ws_size) {   // diagnostic guard: zeros => ws too small
    zero_f_kernel<<<2, 256, 0, stream>>>(out, NG_);
    return;
  }

  zero_f_kernel<<<2048, 256, 0, stream>>>(v_a, (long)NN*D3);
  zero_f_kernel<<<2, 256, 0, stream>>>(out, NG_);
  zero_i_kernel<<<64, 256, 0, stream>>>(counts, NN);
  init_x_kernel<<<(NN*DD + 255)/256, 256, 0, stream>>>(at_no, emb, x);
  prep_w_kernel<<<(3*LSZ + 255)/256, 256, 0, stream>>>(Wm1, Wm2, U, V, Wu1, Wu2, wbh, wbl);
  hist_kernel<<<(NE + 255)/256, 256, 0, stream>>>(ei, pos, counts);
  scan_kernel<<<1, 1024, 0, stream>>>(counts, indptr, NN);
  zero_i_kernel<<<64, 256, 0, stream>>>(counts, NN);
  fill_kernel<<<(NE + 255)/256, 256, 0, stream>>>(ei, pos, indptr, counts, srcs, eg1, eg2);

  const int MB = (NN + 31) / 32;    // 1563
  float* vcur = v_a;
  float* vnext = v_b;
  for (int l = 0; l < 3; l++) {
    const float* Wf_l  = Wf  + (size_t)l*NB_*D3;
    const float* bf_l  = bfp + (size_t)l*D3;
    const float* bm1_l = bm1 + (size_t)l*DD;
    const float* bm2_l = bm2 + (size_t)l*D3;
    const float* bu1_l = bu1 + (size_t)l*DD;
    const float* bu2_l = bu2 + (size_t)l*D3;
    const short* Lh = wbh + (size_t)l*LSZ;
    const short* Ll = wbl + (size_t)l*LSZ;
    const short* Wm1h = Lh,          *Wm1L = Ll;
    const short* Wm2h = Lh + 16384,  *Wm2L = Ll + 16384;
    const short* Uh   = Lh + 65536,  *UL   = Ll + 65536;
    const short* Vh   = Lh + 81920,  *VL   = Ll + 81920;
    const short* Wu1h = Lh + 98304,  *Wu1L = Ll + 98304;
    const short* Wu2h = Lh + 131072, *Wu2L = Ll + 131072;

    // fused node-MLP: x -> t2 (LDS) -> phi slices {phi0, phiS, t1}
    mlp_phi_kernel<<<MB, 512, 0, stream>>>(x, Wm1h, Wm1L, bm1_l, Wm2h, Wm2L, bm2_l,
                                           phi0, phiS, t1, NN);
    // fused: edge sweep + U/V proj + a-MLP + x,v update (x_new/v_new stay in LDS)
    muva_kernel<<<NN/16, 512, 0, stream>>>(phi0, phiS, t1, vcur, vnext, x,
                                           srcs, eg1, eg2, indptr, Wf_l, bf_l,
                                           Uh, UL, Vh, VL,
                                           Wu1h, Wu1L, bu1_l, Wu2h, Wu2L, bu2_l);

    float* tmp = vcur; vcur = vnext; vnext = tmp;
  }

  out_kernel<<<NN/4, 256, 0, stream>>>(x, Wo1, bo1, Wo2, bo2, batch, out);

  (void)in_sizes; (void)n_in; (void)out_size; (void)ws_size;
}